// Round 3
// baseline (24.153 us; speedup 1.0000x reference)
//
#include <hip/hip_runtime.h>
#include <hip/hip_fp16.h>
#include <math.h>

#define D 64
#define NS 64      // S: tokens per shard
#define H 8
#define NSHARD 128 // B * n_shards
#define KPB 8      // k columns per block (2 per wave)
#define NBLK (NSHARD * (D / KPB))   // 1024 blocks = 4/CU exactly
#define TBL 512    // LUT entries over [-8, 8), nearest-neighbor (centers baked)
constexpr float LR = 0.01f;
constexpr float WD = 0.01f;
constexpr float GSCALE = (float)TBL / 16.0f;   // 32 entries per unit g
constexpr float GOFF   = 8.0f * GSCALE;        // 256
constexpr float TMAXN  = 511.0f;               // clamp for nearest index

typedef __attribute__((ext_vector_type(8))) short bf16x8;  // 8 bf16 (4 VGPR)
typedef __attribute__((ext_vector_type(4))) float f32x4;
typedef __attribute__((ext_vector_type(2))) float f32x2;   // -> v_pk_*_f32

__device__ __forceinline__ short f2bf(float f) {           // f32 -> bf16 RNE
    unsigned u = __float_as_uint(f);
    return (short)((u + 0x7FFF + ((u >> 16) & 1)) >> 16);
}

template<int CTRL, int RM>
__device__ __forceinline__ float dpp_add(float v) {
    int t = __builtin_amdgcn_update_dpp(0, __float_as_int(v), CTRL, RM, 0xf, true);
    return v + __int_as_float(t);
}

// LDS layout (39936 B -> 4 blocks/CU):
//   [0,    18432): WT[2][64][72] bf16   -- W0+Wq staging (dead after MFMA phase)
//     overlay:  [0,8192) P2[4 waves][2 slots][8 s][16 quads] float2  (double-buffered)
//               [8192,10240) osh[64][8] f32
//   [18432,35840): XQT[64 j][68 s] u32  (half2(x,q), TRANSPOSED: row=j, col=s)
//   [35840,37888): Esm[64][8] f32  (this block's 8 k-columns of E)
//   [37888,39936): Tl[512] f32 (nearest LUT, cell centers)
#define SM_BYTES 39936
#define OFF_XQT  18432
#define OFF_ESM  35840
#define OFF_TL   37888
#define OFF_OSH  8192

__global__ __launch_bounds__(256, 4) void tnt_fused(const float* __restrict__ X,
                                                    const float* __restrict__ mem0,
                                                    const float* __restrict__ opt,
                                                    const float* __restrict__ Wq,
                                                    float* __restrict__ out) {
    __shared__ __align__(16) char smem[SM_BYTES];
    short*    WT  = (short*)(smem);               // [2][64][72]
    unsigned* XQT = (unsigned*)(smem + OFF_XQT);  // [64][68]
    float (*Esm)[KPB] = (float(*)[KPB])(smem + OFF_ESM);
    float*    Tl  = (float*)(smem + OFF_TL);
    float (*osh)[KPB] = (float(*)[KPB])(smem + OFF_OSH);

    // XCD swizzle: the 8 blocks of a shard land on one XCD's L2 (1024 % 8 == 0)
    const int bid  = ((int)blockIdx.x & 7) * (NBLK / 8) + ((int)blockIdx.x >> 3);
    const int n    = bid >> 3;
    const int kq   = bid & 7;
    const int tid  = threadIdx.x;
    const int wv   = tid >> 6;
    const int lane = tid & 63;
    const int l15  = lane & 15, lhi = lane >> 4;
    const int k0   = (kq << 3) + (wv << 1);       // first of this wave's 2 k-cols

    char* P2b = smem + (wv << 11);                // 2 KB per wave (2 slots x 1 KB)

    const float* Xs = X + n * NS * D;

    // ---- phase 1: stage W0^T and Wq^T bf16 in one pass ----
    {
        const int m     = tid >> 7;            // matrix 0/1
        const int kcol  = tid & 63;            // output column of W
        const int gbase = ((tid >> 6) & 1) * 4;
        const float* Wm = m ? Wq : mem0;
#pragma unroll
        for (int gg = 0; gg < 4; ++gg) {
            const int g = gbase + gg;
            bf16x8 pk;
#pragma unroll
            for (int i = 0; i < 8; ++i)
                pk[i] = f2bf(Wm[(g * 8 + i) * D + kcol]);   // coalesced per i
            *(bf16x8*)(WT + (m * 64 + kcol) * 72 + g * 8) = pk;
        }
    }
    // A-frags (rows wv*16 + l15), shared by both GEMMs
    bf16x8 afrag[2];
    {
        const float* xrow = Xs + (wv * 16 + l15) * D + lhi * 8;
#pragma unroll
        for (int ks = 0; ks < 2; ++ks) {
            const float4 u0 = *(const float4*)(xrow + ks * 32);
            const float4 u1 = *(const float4*)(xrow + ks * 32 + 4);
            bf16x8 a;
            a[0]=f2bf(u0.x); a[1]=f2bf(u0.y); a[2]=f2bf(u0.z); a[3]=f2bf(u0.w);
            a[4]=f2bf(u1.x); a[5]=f2bf(u1.y); a[6]=f2bf(u1.z); a[7]=f2bf(u1.w);
            afrag[ks] = a;
        }
    }
    const float2 m0v  = *(const float2*)(mem0 + lane * D + k0);  // both k-cols
    const f32x2 wdm2 = {WD * m0v.x, WD * m0v.y};
    __syncthreads();

    // ---- phase 2: both GEMMs; E -> Esm (8 cols); xq tile (transposed); LUT ----
    {
        f32x4 accE[4], accQ[4];
#pragma unroll
        for (int nt = 0; nt < 4; ++nt) { accE[nt] = 0; accQ[nt] = 0; }
#pragma unroll
        for (int nt = 0; nt < 4; ++nt) {
            const int col = nt * 16 + l15;
#pragma unroll
            for (int ks = 0; ks < 2; ++ks) {
                const bf16x8 b0 = *(const bf16x8*)(WT + col * 72 + ks * 32 + lhi * 8);
                const bf16x8 b1 = *(const bf16x8*)(WT + (64 + col) * 72 + ks * 32 + lhi * 8);
                accE[nt] = __builtin_amdgcn_mfma_f32_16x16x32_bf16(afrag[ks], b0, accE[nt], 0,0,0);
                accQ[nt] = __builtin_amdgcn_mfma_f32_16x16x32_bf16(afrag[ks], b1, accQ[nt], 0,0,0);
            }
        }
        // E epilogue: cols kq*8+j (j=0..7) -> Esm[row][j].
        const float c = (2.0f / (float)D) * GSCALE;
        if ((l15 >> 3) == (kq & 1)) {
            const int nt_e = kq >> 1;            // wave-uniform select (no scratch)
            const f32x4 aE = (nt_e == 0) ? accE[0] : (nt_e == 1) ? accE[1]
                           : (nt_e == 2) ? accE[2] : accE[3];
            const int j = l15 & 7;
#pragma unroll
            for (int r = 0; r < 4; ++r) {
                const int row = wv * 16 + lhi * 4 + r;
                const int col = (kq << 3) + j;
                Esm[row][j] = c * (aE[r] - Xs[row * D + col]);
            }
        }
        // Q epilogue: xq tile half2(x, q), stored TRANSPOSED: XQT[j][s]
#pragma unroll
        for (int nt = 0; nt < 4; ++nt) {
#pragma unroll
            for (int r = 0; r < 4; ++r) {
                const int row = wv * 16 + lhi * 4 + r;      // s
                const int col = nt * 16 + l15;              // j
                const __half2 h = __halves2half2(__float2half_rn(Xs[row * D + col]),
                                                 __float2half_rn(accQ[nt][r]));
                XQT[col * 68 + row] = *(const unsigned*)&h;
            }
        }
    }
    {   // LR-scaled nearest LUT: entry j = f at cell center g=(j+0.5-256)/32
        float w1d[H], b1d[H], w2[H];
#pragma unroll
        for (int h = 0; h < H; ++h) {
            w1d[h] = 2.0f * opt[h]; b1d[h] = 2.0f * opt[H + h]; w2[h] = opt[2 * H + h];
        }
        const float b2 = opt[3 * H];
#pragma unroll
        for (int jj = tid; jj < TBL; jj += 256) {      // 2 iterations
            const float g = ((float)jj + 0.5f - GOFF) / GSCALE;
            float acc = b2;
#pragma unroll
            for (int h = 0; h < H; ++h) {
                const float u = __expf(fmaf(w1d[h], g, b1d[h]));   // e^{2y}
                acc = fmaf(w2[h], (u - 1.0f) * __builtin_amdgcn_rcpf(u + 1.0f), acc);
            }
            Tl[jj] = LR * acc;
        }
    }
    __syncthreads();   // WT reads done (overlay free); Esm/XQT/Tl ready

    const float2 ee = *(const float2*)&Esm[lane][wv << 1];
    const float e0 = ee.x;     // E[n, s=lane, k0]   * GSCALE
    const float e1 = ee.y;     // E[n, s=lane, k0+1] * GSCALE

    // ---- main loop: 8 batches of 8 steps, 2 k-columns, pipelined reduction ----
    const unsigned* xrow = XQT + lane * 68;    // this lane's j-column, along s
    uint4 xa = *(const uint4*)(xrow + 0);
    uint4 xb = *(const uint4*)(xrow + 4);
    f32x2 cum = {m0v.x, m0v.y};
    const int g8 = lane >> 3;
    const int h8 = lane & 7;
    const int qd = lane >> 2;
    const bool qlead = (lane & 3) == 0;

#pragma unroll 1
    for (int b = 0; b < 8; ++b) {
        const unsigned xw[8] = {xa.x, xa.y, xa.z, xa.w, xb.x, xb.y, xb.z, xb.w};
        float q8[8];
        f32x2 v01[8];
#pragma unroll
        for (int u = 0; u < 8; ++u) {          // independent across u AND k
            const int s = (b << 3) + u;
            const float ek0 = __int_as_float(
                __builtin_amdgcn_readlane(__float_as_int(e0), s));
            const float ek1 = __int_as_float(
                __builtin_amdgcn_readlane(__float_as_int(e1), s));
            const __half2 hv = *(const __half2*)&xw[u];
            const float xv = __low2float(hv);
            q8[u] = __high2float(hv);
            const float t0 = __builtin_amdgcn_fmed3f(fmaf(xv, ek0, GOFF), 0.0f, TMAXN);
            const float t1 = __builtin_amdgcn_fmed3f(fmaf(xv, ek1, GOFF), 0.0f, TMAXN);
            f32x2 g2; g2.x = Tl[(int)t0]; g2.y = Tl[(int)t1];   // b32 gathers
            v01[u] = g2 + wdm2;                // v_pk_add_f32
        }
        if (b < 7) {                           // prefetch next batch's x/q
            xa = *(const uint4*)(xrow + (b + 1) * 8);
            xb = *(const uint4*)(xrow + (b + 1) * 8 + 4);
        }
        float2* slot = (float2*)(P2b + ((b & 1) << 10));
#pragma unroll
        for (int u = 0; u < 8; ++u) {          // chain + quad-reduce + stash
            cum = cum - v01[u];                // v_pk_add_f32 (neg)
            f32x2 p; p.x = q8[u]; p.y = q8[u];
            p = p * cum;                       // v_pk_mul_f32
            float x0 = dpp_add<0xB1, 0xf>(p.x);   // xor 1
            x0       = dpp_add<0x4E, 0xf>(x0);    // xor 2
            float x1 = dpp_add<0xB1, 0xf>(p.y);
            x1       = dpp_add<0x4E, 0xf>(x1);
            if (qlead)
                slot[u * 16 + qd] = make_float2(x0, x1);
        }
        // pipelined tail for batch b-1: its P2 writes are 1 iteration old -> no stall
        if (b > 0) {
            const int bb = b - 1;
            const float4 pp = *(const float4*)(P2b + ((bb & 1) << 10) + g8 * 128 + h8 * 16);
            float s0 = pp.x + pp.z;
            float s1 = pp.y + pp.w;
            s0 = dpp_add<0xB1, 0xf>(s0); s0 = dpp_add<0x4E, 0xf>(s0); s0 = dpp_add<0x141, 0xf>(s0);
            s1 = dpp_add<0xB1, 0xf>(s1); s1 = dpp_add<0x4E, 0xf>(s1); s1 = dpp_add<0x141, 0xf>(s1);
            if (h8 == 0)
                *(float2*)&osh[(bb << 3) + g8][wv << 1] = make_float2(s0, s1);
        }
        __builtin_amdgcn_wave_barrier();       // keep cross-iteration DS order
    }
    {   // drain tail for batch 7
        const float4 pp = *(const float4*)(P2b + (1 << 10) + g8 * 128 + h8 * 16);
        float s0 = pp.x + pp.z;
        float s1 = pp.y + pp.w;
        s0 = dpp_add<0xB1, 0xf>(s0); s0 = dpp_add<0x4E, 0xf>(s0); s0 = dpp_add<0x141, 0xf>(s0);
        s1 = dpp_add<0xB1, 0xf>(s1); s1 = dpp_add<0x4E, 0xf>(s1); s1 = dpp_add<0x141, 0xf>(s1);
        if (h8 == 0)
            *(float2*)&osh[(7 << 3) + g8][wv << 1] = make_float2(s0, s1);
    }

    __syncthreads();
    // out: this block's 8 columns for all 64 s; 2 floats per thread (b64 store)
    const int s_ = tid >> 2;
    const int c2 = (tid & 3) << 1;
    const float2 o = *(const float2*)&osh[s_][c2];
    *(float2*)(out + (n * NS + s_) * D + (kq << 3) + c2) = o;
}

extern "C" void kernel_launch(void* const* d_in, const int* in_sizes, int n_in,
                              void* d_out, int out_size, void* d_ws, size_t ws_size,
                              hipStream_t stream) {
    const float* X    = (const float*)d_in[0];   // (4,2048,64)
    const float* mem0 = (const float*)d_in[1];   // (4096,)
    const float* opt  = (const float*)d_in[2];   // (25,)
    const float* Wq   = (const float*)d_in[3];   // (64,64)
    float* out = (float*)d_out;

    tnt_fused<<<dim3(NBLK), dim3(256), 0, stream>>>(X, mem0, opt, Wq, out);
}

// Round 4
// 22.577 us; speedup vs baseline: 1.0698x; 1.0698x over previous
//
#include <hip/hip_runtime.h>
#include <hip/hip_fp16.h>
#include <math.h>

#define D 64
#define NS 64      // S: tokens per shard
#define H 8
#define NSHARD 128 // B * n_shards
#define KPB 8      // k columns per block (2 per wave)
#define NBLK (NSHARD * (D / KPB))   // 1024 blocks = 4/CU exactly
#define TBL 512    // LUT entries over [-8, 8), nearest-neighbor (centers baked)
constexpr float LR = 0.01f;
constexpr float WD = 0.01f;
constexpr float GSCALE = (float)TBL / 16.0f;   // 32 entries per unit g
constexpr float GOFF   = 8.0f * GSCALE;        // 256
constexpr float TMAXN  = 511.0f;               // clamp for nearest index

typedef __attribute__((ext_vector_type(8))) short bf16x8;  // 8 bf16 (4 VGPR)
typedef __attribute__((ext_vector_type(4))) float f32x4;
typedef __attribute__((ext_vector_type(2))) float f32x2;   // -> v_pk_*_f32

__device__ __forceinline__ short f2bf(float f) {           // f32 -> bf16 RNE
    unsigned u = __float_as_uint(f);
    return (short)((u + 0x7FFF + ((u >> 16) & 1)) >> 16);
}

template<int CTRL, int RM>
__device__ __forceinline__ float dpp_add(float v) {
    int t = __builtin_amdgcn_update_dpp(0, __float_as_int(v), CTRL, RM, 0xf, true);
    return v + __int_as_float(t);
}

// LDS layout (39936 B -> 4 blocks/CU):
//   [0,    18432): WT[2][64][72] bf16   -- W0+Wq staging (dead after MFMA phase)
//     overlay (main loop): o4 partial-sum buffer, word(r,s,col) = r*648 + s*10 + col
//       (4 row-copies x 64 s x 8 cols + pad; 10324 B; summed in epilogue)
//   [18432,35840): XQT[64 j][68 s] u32  (half2(x,q), TRANSPOSED: row=j, col=s)
//   [35840,37888): Esm[64][8] f32  (this block's 8 k-columns of E)
//   [37888,39936): Tl[512] f32 (nearest LUT, cell centers)
#define SM_BYTES 39936
#define OFF_XQT  18432
#define OFF_ESM  35840
#define OFF_TL   37888
#define O4_R     648   // words per row-copy (648%32=8 -> rows bank-shifted)
#define O4_S     10    // words per s (even -> aligned float2 epilogue reads)

__global__ __launch_bounds__(256, 4) void tnt_fused(const float* __restrict__ X,
                                                    const float* __restrict__ mem0,
                                                    const float* __restrict__ opt,
                                                    const float* __restrict__ Wq,
                                                    float* __restrict__ out) {
    __shared__ __align__(16) char smem[SM_BYTES];
    short*    WT  = (short*)(smem);               // [2][64][72]
    unsigned* XQT = (unsigned*)(smem + OFF_XQT);  // [64][68]
    float (*Esm)[KPB] = (float(*)[KPB])(smem + OFF_ESM);
    float*    Tl  = (float*)(smem + OFF_TL);
    float*    o4  = (float*)(smem);               // overlay after WT is dead

    // XCD swizzle: the 8 blocks of a shard land on one XCD's L2 (1024 % 8 == 0)
    const int bid  = ((int)blockIdx.x & 7) * (NBLK / 8) + ((int)blockIdx.x >> 3);
    const int n    = bid >> 3;
    const int kq   = bid & 7;
    const int tid  = threadIdx.x;
    const int wv   = tid >> 6;
    const int lane = tid & 63;
    const int l15  = lane & 15, lhi = lane >> 4;
    const int k0   = (kq << 3) + (wv << 1);       // first of this wave's 2 k-cols

    const float* Xs = X + n * NS * D;

    // ---- phase 1: stage W0^T and Wq^T bf16 in one pass ----
    {
        const int m     = tid >> 7;            // matrix 0/1
        const int kcol  = tid & 63;            // output column of W
        const int gbase = ((tid >> 6) & 1) * 4;
        const float* Wm = m ? Wq : mem0;
#pragma unroll
        for (int gg = 0; gg < 4; ++gg) {
            const int g = gbase + gg;
            bf16x8 pk;
#pragma unroll
            for (int i = 0; i < 8; ++i)
                pk[i] = f2bf(Wm[(g * 8 + i) * D + kcol]);   // coalesced per i
            *(bf16x8*)(WT + (m * 64 + kcol) * 72 + g * 8) = pk;
        }
    }
    // A-frags (rows wv*16 + l15), shared by both GEMMs
    bf16x8 afrag[2];
    {
        const float* xrow = Xs + (wv * 16 + l15) * D + lhi * 8;
#pragma unroll
        for (int ks = 0; ks < 2; ++ks) {
            const float4 u0 = *(const float4*)(xrow + ks * 32);
            const float4 u1 = *(const float4*)(xrow + ks * 32 + 4);
            bf16x8 a;
            a[0]=f2bf(u0.x); a[1]=f2bf(u0.y); a[2]=f2bf(u0.z); a[3]=f2bf(u0.w);
            a[4]=f2bf(u1.x); a[5]=f2bf(u1.y); a[6]=f2bf(u1.z); a[7]=f2bf(u1.w);
            afrag[ks] = a;
        }
    }
    const float2 m0v  = *(const float2*)(mem0 + lane * D + k0);  // both k-cols
    const f32x2 wdm2 = {WD * m0v.x, WD * m0v.y};
    __syncthreads();

    // ---- phase 2: both GEMMs; E -> Esm (8 cols); xq tile (transposed); LUT ----
    {
        f32x4 accE[4], accQ[4];
#pragma unroll
        for (int nt = 0; nt < 4; ++nt) { accE[nt] = 0; accQ[nt] = 0; }
#pragma unroll
        for (int nt = 0; nt < 4; ++nt) {
            const int col = nt * 16 + l15;
#pragma unroll
            for (int ks = 0; ks < 2; ++ks) {
                const bf16x8 b0 = *(const bf16x8*)(WT + col * 72 + ks * 32 + lhi * 8);
                const bf16x8 b1 = *(const bf16x8*)(WT + (64 + col) * 72 + ks * 32 + lhi * 8);
                accE[nt] = __builtin_amdgcn_mfma_f32_16x16x32_bf16(afrag[ks], b0, accE[nt], 0,0,0);
                accQ[nt] = __builtin_amdgcn_mfma_f32_16x16x32_bf16(afrag[ks], b1, accQ[nt], 0,0,0);
            }
        }
        // E epilogue: cols kq*8+j (j=0..7) -> Esm[row][j].
        const float c = (2.0f / (float)D) * GSCALE;
        if ((l15 >> 3) == (kq & 1)) {
            const int nt_e = kq >> 1;            // wave-uniform select (no scratch)
            const f32x4 aE = (nt_e == 0) ? accE[0] : (nt_e == 1) ? accE[1]
                           : (nt_e == 2) ? accE[2] : accE[3];
            const int j = l15 & 7;
#pragma unroll
            for (int r = 0; r < 4; ++r) {
                const int row = wv * 16 + lhi * 4 + r;
                const int col = (kq << 3) + j;
                Esm[row][j] = c * (aE[r] - Xs[row * D + col]);
            }
        }
        // Q epilogue: xq tile half2(x, q), stored TRANSPOSED: XQT[j][s]
#pragma unroll
        for (int nt = 0; nt < 4; ++nt) {
#pragma unroll
            for (int r = 0; r < 4; ++r) {
                const int row = wv * 16 + lhi * 4 + r;      // s
                const int col = nt * 16 + l15;              // j
                const __half2 h = __halves2half2(__float2half_rn(Xs[row * D + col]),
                                                 __float2half_rn(accQ[nt][r]));
                XQT[col * 68 + row] = *(const unsigned*)&h;
            }
        }
    }
    {   // LR-scaled nearest LUT: entry j = f at cell center g=(j+0.5-256)/32
        float w1d[H], b1d[H], w2[H];
#pragma unroll
        for (int h = 0; h < H; ++h) {
            w1d[h] = 2.0f * opt[h]; b1d[h] = 2.0f * opt[H + h]; w2[h] = opt[2 * H + h];
        }
        const float b2 = opt[3 * H];
#pragma unroll
        for (int jj = tid; jj < TBL; jj += 256) {      // 2 iterations
            const float g = ((float)jj + 0.5f - GOFF) / GSCALE;
            float acc = b2;
#pragma unroll
            for (int h = 0; h < H; ++h) {
                const float u = __expf(fmaf(w1d[h], g, b1d[h]));   // e^{2y}
                acc = fmaf(w2[h], (u - 1.0f) * __builtin_amdgcn_rcpf(u + 1.0f), acc);
            }
            Tl[jj] = LR * acc;
        }
    }
    __syncthreads();   // WT reads done (overlay free); Esm/XQT/Tl ready

    const float2 ee = *(const float2*)&Esm[lane][wv << 1];
    const float e0 = ee.x;     // E[n, s=lane, k0]   * GSCALE
    const float e1 = ee.y;     // E[n, s=lane, k0+1] * GSCALE

    // ---- main loop: 8 fully-unrolled batches; DPP reduce; 1 ds_write/batch ----
    const unsigned* xrow = XQT + lane * 68;    // this lane's j-column, along s
    f32x2 cum = {m0v.x, m0v.y};

    // lane -> (row-copy r, step u, col k) for the partial write
    const int r4  = lane >> 4;
    const int w16 = lane & 15;
    const bool selk  = (w16 & 1) != 0;
    const bool selu0 = (w16 & 2) != 0;
    const bool selu1 = (w16 & 4) != 0;
    const bool selu2 = (w16 & 8) != 0;
    float* wbase = o4 + r4 * O4_R + (w16 >> 1) * O4_S + (wv << 1) + (w16 & 1);

#pragma unroll
    for (int b = 0; b < 8; ++b) {
        const uint4 xa = *(const uint4*)(xrow + b * 8);
        const uint4 xb = *(const uint4*)(xrow + b * 8 + 4);
        const unsigned xw[8] = {xa.x, xa.y, xa.z, xa.w, xb.x, xb.y, xb.z, xb.w};
        float q8[8];
        f32x2 v01[8];
#pragma unroll
        for (int u = 0; u < 8; ++u) {          // independent across u AND k
            const int s = (b << 3) + u;
            const float ek0 = __int_as_float(
                __builtin_amdgcn_readlane(__float_as_int(e0), s));
            const float ek1 = __int_as_float(
                __builtin_amdgcn_readlane(__float_as_int(e1), s));
            const __half2 hv = *(const __half2*)&xw[u];
            const float xv = __low2float(hv);
            q8[u] = __high2float(hv);
            const float t0 = __builtin_amdgcn_fmed3f(fmaf(xv, ek0, GOFF), 0.0f, TMAXN);
            const float t1 = __builtin_amdgcn_fmed3f(fmaf(xv, ek1, GOFF), 0.0f, TMAXN);
            f32x2 g2; g2.x = Tl[(int)t0]; g2.y = Tl[(int)t1];   // b32 gathers
            v01[u] = g2 + wdm2;                // v_pk_add_f32
        }
        float p0s[8], p1s[8];
#pragma unroll
        for (int u = 0; u < 8; ++u) {          // chain + full-row DPP reduce
            cum = cum - v01[u];                // v_pk_add_f32 (neg)
            f32x2 qq; qq.x = q8[u]; qq.y = q8[u];
            const f32x2 p = qq * cum;          // v_pk_mul_f32
            float x0 = dpp_add<0xB1,  0xf>(p.x);   // xor 1
            x0       = dpp_add<0x4E,  0xf>(x0);    // xor 2
            x0       = dpp_add<0x141, 0xf>(x0);    // row_half_mirror -> 8-sum
            x0       = dpp_add<0x140, 0xf>(x0);    // row_mirror      -> 16-sum
            float x1 = dpp_add<0xB1,  0xf>(p.y);
            x1       = dpp_add<0x4E,  0xf>(x1);
            x1       = dpp_add<0x141, 0xf>(x1);
            x1       = dpp_add<0x140, 0xf>(x1);
            p0s[u] = x0; p1s[u] = x1;
        }
        // per-lane select of its (u,k) 16-row partial (15 cndmask, static idx)
        const float t0_ = selk ? p1s[0] : p0s[0];
        const float t1_ = selk ? p1s[1] : p0s[1];
        const float t2_ = selk ? p1s[2] : p0s[2];
        const float t3_ = selk ? p1s[3] : p0s[3];
        const float t4_ = selk ? p1s[4] : p0s[4];
        const float t5_ = selk ? p1s[5] : p0s[5];
        const float t6_ = selk ? p1s[6] : p0s[6];
        const float t7_ = selk ? p1s[7] : p0s[7];
        const float a0 = selu0 ? t1_ : t0_;
        const float a1 = selu0 ? t3_ : t2_;
        const float a2 = selu0 ? t5_ : t4_;
        const float a3 = selu0 ? t7_ : t6_;
        const float b0 = selu1 ? a1 : a0;
        const float b1 = selu1 ? a3 : a2;
        const float val = selu2 ? b1 : b0;
        wbase[b * (8 * O4_S)] = val;           // ds_write_b32, imm offset 320*b
    }

    __syncthreads();
    // epilogue: sum the 4 row-copies; 2 floats per thread (b64 reads/store)
    const int s_ = tid >> 2;
    const int c2 = (tid & 3) << 1;
    float ox = 0.0f, oy = 0.0f;
#pragma unroll
    for (int r = 0; r < 4; ++r) {
        const float2 v = *(const float2*)&o4[r * O4_R + s_ * O4_S + c2];
        ox += v.x; oy += v.y;
    }
    *(float2*)(out + (n * NS + s_) * D + (kq << 3) + c2) = make_float2(ox, oy);
}

extern "C" void kernel_launch(void* const* d_in, const int* in_sizes, int n_in,
                              void* d_out, int out_size, void* d_ws, size_t ws_size,
                              hipStream_t stream) {
    const float* X    = (const float*)d_in[0];   // (4,2048,64)
    const float* mem0 = (const float*)d_in[1];   // (4096,)
    const float* opt  = (const float*)d_in[2];   // (25,)
    const float* Wq   = (const float*)d_in[3];   // (64,64)
    float* out = (float*)d_out;

    tnt_fused<<<dim3(NBLK), dim3(256), 0, stream>>>(X, mem0, opt, Wq, out);
}